// Round 1
// baseline (191.786 us; speedup 1.0000x reference)
//
#include <hip/hip_runtime.h>

// GraphSage on MI355X — round 10.
//   prep  : feat fp32 -> fb bf16 (GEMM self operand) + f8 fp8 e4m3 [N][128B] (gather src)
//           + w1,w2 -> w1T,w2T bf16 [n][k]
//   k1_agg: register gather (no LDS, no full-drain): 16 x uint4 loads per lane in two
//           batches of 8, consumed as they land. ~16 waves/CU (was 10 with LDS-DMA).
//   g1    : h1 = [fb | agg] @ w1T.  NO LDS, NO barriers: A rows are wave-private, so
//           fragments load straight global->VGPR; W re-read from L2 (64 KB table, hot).
//           12 waves/CU, pure streaming — removes the per-K-chunk vmcnt(0) barrier drain.
//   g2    : out = [h1[node] | mean h1[nbr]] @ w2T. 512 one-wave blocks (16 rows each),
//           wave-private LDS slice -> no __syncthreads, all 256 CUs covered (was 128).

#define N_NODES 100000
#define DEG     16
#define FDIM    128
#define HDIM    128
#define B_NODES 8192

typedef __attribute__((ext_vector_type(8))) short bf16x8;
typedef __attribute__((ext_vector_type(8))) unsigned short u16x8;
typedef __attribute__((ext_vector_type(4))) float f32x4;
typedef __attribute__((ext_vector_type(2))) float f32x2;

static __device__ __forceinline__ unsigned short f2bf(float f) {
    union { float f; unsigned u; } v; v.f = f;
    unsigned r = v.u + 0x7fff + ((v.u >> 16) & 1);   // RNE
    return (unsigned short)(r >> 16);
}
static __device__ __forceinline__ float bf2f(unsigned short b) {
    union { unsigned u; float f; } v; v.u = ((unsigned)b) << 16;
    return v.f;
}

// blocks 0..6249: cast feat -> fb (bf16) + f8 (fp8). blocks 6250..6265: w1/w2 transpose.
__global__ __launch_bounds__(256)
void prep(const float* __restrict__ feat, const float* __restrict__ w1,
          const float* __restrict__ w2, unsigned short* __restrict__ fb,
          unsigned char* __restrict__ f8,
          unsigned short* __restrict__ w1T, unsigned short* __restrict__ w2T) {
    if (blockIdx.x < 6250) {
        long e = ((long)blockIdx.x * 256 + threadIdx.x) * 8;   // 6250*256*8 = 12.8M exact
        float4 v0 = *(const float4*)(feat + e);
        float4 v1 = *(const float4*)(feat + e + 4);
        u16x8 ob;
        ob[0] = f2bf(v0.x); ob[1] = f2bf(v0.y); ob[2] = f2bf(v0.z); ob[3] = f2bf(v0.w);
        ob[4] = f2bf(v1.x); ob[5] = f2bf(v1.y); ob[6] = f2bf(v1.z); ob[7] = f2bf(v1.w);
        *(u16x8*)(fb + e) = ob;
        int p0 = 0, p1 = 0;
        p0 = __builtin_amdgcn_cvt_pk_fp8_f32(v0.x, v0.y, p0, false);
        p0 = __builtin_amdgcn_cvt_pk_fp8_f32(v0.z, v0.w, p0, true);
        p1 = __builtin_amdgcn_cvt_pk_fp8_f32(v1.x, v1.y, p1, false);
        p1 = __builtin_amdgcn_cvt_pk_fp8_f32(v1.z, v1.w, p1, true);
        uint2 o8; o8.x = (unsigned)p0; o8.y = (unsigned)p1;
        *(uint2*)(f8 + e) = o8;
    } else {
        int bid = blockIdx.x - 6250;
        const float* w = (bid < 8) ? w1 : w2;
        unsigned short* wT = (bid < 8) ? w1T : w2T;
        int kb = (bid & 7) * 32;
        int n = threadIdx.x & 127, dk = threadIdx.x >> 7;
#pragma unroll
        for (int i = 0; i < 16; ++i) {
            int k = kb + dk * 16 + i;
            wT[n * 256 + k] = f2bf(w[k * 128 + n]);   // read coalesced over n
        }
    }
}

// Register gather: 32 nodes/block (8 lanes x 16 B = full 128-B row per node).
// No LDS -> occupancy VGPR-limited (~16 waves/CU); loads consumed as they land
// (per-use waitcnt) instead of a vmcnt(0) full drain.
__global__ __launch_bounds__(256, 4)
void k1_agg(const unsigned char* __restrict__ f8, const int* __restrict__ nbr,
            unsigned short* __restrict__ agg) {
    const int t = threadIdx.x;
    const int node = blockIdx.x * 32 + (t >> 3);   // 3125*32 = 100000 exact
    const int sub = t & 7;
    const int* idx = nbr + node * DEG;
    int4 i0 = *(const int4*)(idx);
    int4 i1 = *(const int4*)(idx + 4);
    int4 i2 = *(const int4*)(idx + 8);
    int4 i3 = *(const int4*)(idx + 12);
    const int id[16] = {i0.x, i0.y, i0.z, i0.w, i1.x, i1.y, i1.z, i1.w,
                        i2.x, i2.y, i2.z, i2.w, i3.x, i3.y, i3.z, i3.w};

    f32x2 s2[8];
#pragma unroll
    for (int j = 0; j < 8; ++j) s2[j] = (f32x2){0.f, 0.f};

    uint4 v[8];
#pragma unroll
    for (int h = 0; h < 2; ++h) {
#pragma unroll
        for (int d = 0; d < 8; ++d)
            v[d] = *(const uint4*)(f8 + (long)id[h * 8 + d] * 128 + sub * 16);
#pragma unroll
        for (int d = 0; d < 8; ++d) {
            s2[0] += __builtin_amdgcn_cvt_pk_f32_fp8((int)v[d].x, false);
            s2[1] += __builtin_amdgcn_cvt_pk_f32_fp8((int)v[d].x, true);
            s2[2] += __builtin_amdgcn_cvt_pk_f32_fp8((int)v[d].y, false);
            s2[3] += __builtin_amdgcn_cvt_pk_f32_fp8((int)v[d].y, true);
            s2[4] += __builtin_amdgcn_cvt_pk_f32_fp8((int)v[d].z, false);
            s2[5] += __builtin_amdgcn_cvt_pk_f32_fp8((int)v[d].z, true);
            s2[6] += __builtin_amdgcn_cvt_pk_f32_fp8((int)v[d].w, false);
            s2[7] += __builtin_amdgcn_cvt_pk_f32_fp8((int)v[d].w, true);
        }
    }

    u16x8 o0, o1;
#pragma unroll
    for (int j = 0; j < 8; ++j) {
        o0[j] = f2bf(s2[j >> 1][j & 1] * 0.0625f);
        o1[j] = f2bf(s2[4 + (j >> 1)][j & 1] * 0.0625f);
    }
    unsigned short* dst = agg + (long)node * 128 + sub * 16;
    *(u16x8*)dst = o0;
    *(u16x8*)(dst + 8) = o1;
}

// GEMM: h1[N,128] = [fb | agg] @ w1T. 128 rows/block, 32 rows/wave.
// A rows are wave-private -> fragments load global->VGPR directly. No LDS, no
// __syncthreads, no vmcnt(0) drain: the compiler pipelines the 80 VMEM loads
// against 128 MFMAs per wave; occupancy (12 waves/CU) covers the rest.
__global__ __launch_bounds__(256, 3)
void g1(const unsigned short* __restrict__ fb, const unsigned short* __restrict__ agg,
        const unsigned short* __restrict__ w1T, unsigned short* __restrict__ h1) {
    const int t = threadIdx.x, wave = t >> 6, lane = t & 63;
    const int m16 = lane & 15, quad = lane >> 4;
    const long row0 = (long)blockIdx.x * 128 + wave * 32;

    f32x4 acc[2][8] = {};
#pragma unroll
    for (int kc = 0; kc < 8; ++kc) {
        const unsigned short* As = (kc < 4) ? (fb + kc * 32) : (agg + (kc - 4) * 32);
        // rows beyond N read into the adjacent ws buffer (in-bounds garbage, masked on store)
        bf16x8 a0 = *(const bf16x8*)(As + (row0 + m16) * 128 + quad * 8);
        bf16x8 a1 = *(const bf16x8*)(As + (row0 + 16 + m16) * 128 + quad * 8);
#pragma unroll
        for (int nt = 0; nt < 8; ++nt) {
            bf16x8 bv = *(const bf16x8*)(w1T + (nt * 16 + m16) * 256 + kc * 32 + quad * 8);
            acc[0][nt] = __builtin_amdgcn_mfma_f32_16x16x32_bf16(a0, bv, acc[0][nt], 0, 0, 0);
            acc[1][nt] = __builtin_amdgcn_mfma_f32_16x16x32_bf16(a1, bv, acc[1][nt], 0, 0, 0);
        }
    }

    // C layout: row = quad*4 + reg, col = nt*16 + m16
#pragma unroll
    for (int mt = 0; mt < 2; ++mt)
#pragma unroll
        for (int reg = 0; reg < 4; ++reg) {
            long grow = row0 + mt * 16 + quad * 4 + reg;
            if (grow >= N_NODES) continue;
#pragma unroll
            for (int nt = 0; nt < 8; ++nt)
                h1[grow * HDIM + nt * 16 + m16] = f2bf(acc[mt][nt][reg]);
        }
}

// Layer 2 fused: 16 batch rows per single-wave block, 512 blocks (all CUs covered).
// X2 slice is wave-private -> no barrier; compiler orders ds_write->ds_read via lgkmcnt.
__global__ __launch_bounds__(64)
void g2_fused(const unsigned short* __restrict__ h1, const unsigned short* __restrict__ w2T,
              const int* __restrict__ nbr, const int* __restrict__ nodes,
              float* __restrict__ out) {
    __shared__ unsigned short X2[16][264];
    const int lane = threadIdx.x;
    const int m16 = lane & 15, quad = lane >> 4;
    const int b0 = blockIdx.x * 16;               // 512*16 = 8192 exact
    const int colb = m16 * 8;

#pragma unroll
    for (int g = 0; g < 4; ++g) {
        int Ln = g * 4 + quad;
        int node = nodes[b0 + Ln];
        *(u16x8*)(&X2[Ln][colb]) = *(const u16x8*)(h1 + (long)node * HDIM + colb);
        const int* idx = nbr + node * DEG;
        float s[8] = {0.f, 0.f, 0.f, 0.f, 0.f, 0.f, 0.f, 0.f};
#pragma unroll
        for (int d = 0; d < DEG; ++d) {
            int nb = idx[d];
            u16x8 v = *(const u16x8*)(h1 + (long)nb * HDIM + colb);
#pragma unroll
            for (int j = 0; j < 8; ++j) s[j] += bf2f(v[j]);
        }
        u16x8 o;
#pragma unroll
        for (int j = 0; j < 8; ++j) o[j] = f2bf(s[j] * 0.0625f);
        *(u16x8*)(&X2[Ln][128 + colb]) = o;
    }

    f32x4 acc[8] = {};
#pragma unroll
    for (int kc = 0; kc < 8; ++kc) {
        bf16x8 a = *(const bf16x8*)(&X2[m16][kc * 32 + quad * 8]);
#pragma unroll
        for (int nt = 0; nt < 8; ++nt) {
            bf16x8 b = *(const bf16x8*)(w2T + (nt * 16 + m16) * 256 + kc * 32 + quad * 8);
            acc[nt] = __builtin_amdgcn_mfma_f32_16x16x32_bf16(a, b, acc[nt], 0, 0, 0);
        }
    }

#pragma unroll
    for (int nt = 0; nt < 8; ++nt)
#pragma unroll
        for (int reg = 0; reg < 4; ++reg) {
            int row = b0 + quad * 4 + reg;
            out[(long)row * 128 + nt * 16 + m16] = acc[nt][reg];
        }
}

extern "C" void kernel_launch(void* const* d_in, const int* in_sizes, int n_in,
                              void* d_out, int out_size, void* d_ws, size_t ws_size,
                              hipStream_t stream) {
    const float* feat  = (const float*)d_in[0];
    const float* w1    = (const float*)d_in[1];
    const float* w2    = (const float*)d_in[2];
    const int*   nbr   = (const int*)d_in[3];
    const int*   nodes = (const int*)d_in[4];
    float* out = (float*)d_out;

    char* ws = (char*)d_ws;
    unsigned short* fb  = (unsigned short*)ws;                       // N*128 bf16 = 25.6 MB
    unsigned char*  f8  = (unsigned char*)(ws + 25600000);           // N*128 fp8  = 12.8 MB
    unsigned short* agg = (unsigned short*)(ws + 38400000);          // N*128 bf16 = 25.6 MB
    unsigned short* h1  = (unsigned short*)(ws + 64000000);          // N*128 bf16 = 25.6 MB
    unsigned short* w1T = (unsigned short*)(ws + 89600000);          // 64 KB
    unsigned short* w2T = (unsigned short*)(ws + 89665536);          // 64 KB

    prep<<<6266, 256, 0, stream>>>(feat, w1, w2, fb, f8, w1T, w2T);
    k1_agg<<<3125, 256, 0, stream>>>(f8, nbr, agg);
    g1<<<(N_NODES + 127) / 128, 256, 0, stream>>>(fb, agg, w1T, h1);
    g2_fused<<<B_NODES / 64 * 4, 64, 0, stream>>>(h1, w2T, nbr, nodes, out);
}

// Round 2
// 170.791 us; speedup vs baseline: 1.1229x; 1.1229x over previous
//
#include <hip/hip_runtime.h>

// GraphSage on MI355X — round 11.
//   prep  : feat fp32 -> fb bf16 (GEMM self operand) + f8 fp8 e4m3 [N][128B] (gather src)
//           + w1,w2 -> w1T,w2T bf16 [n][k]
//   k1_agg: (round-9 form) async-DMA gather, 1-wave blocks, wave-local vmcnt(0),
//           packed f32x2 adds from wave-private LDS. 16 KB LDS -> 10 blocks/CU.
//   g1    : h1 = [fb | agg] @ w1T.  NEW: W staged ONCE into LDS in MFMA-fragment order
//           (source-permuted global_load_lds, lane-linear conflict-free ds_read_b128);
//           A panel (16 x bf16x8 = 64 VGPR) issued global->VGPR up front; ONE barrier
//           drains everything; K-loop is pure ds_read+MFMA, no barriers, no vmem waits.
//   g2    : (round-9 form) out = [h1[node] | mean h1[nbr]] @ w2T, 64 rows/block.

#define N_NODES 100000
#define DEG     16
#define FDIM    128
#define HDIM    128
#define B_NODES 8192

typedef __attribute__((ext_vector_type(8))) short bf16x8;
typedef __attribute__((ext_vector_type(8))) unsigned short u16x8;
typedef __attribute__((ext_vector_type(4))) float f32x4;
typedef __attribute__((ext_vector_type(2))) float f32x2;

static __device__ __forceinline__ unsigned short f2bf(float f) {
    union { float f; unsigned u; } v; v.f = f;
    unsigned r = v.u + 0x7fff + ((v.u >> 16) & 1);   // RNE
    return (unsigned short)(r >> 16);
}
static __device__ __forceinline__ float bf2f(unsigned short b) {
    union { unsigned u; float f; } v; v.u = ((unsigned)b) << 16;
    return v.f;
}

// blocks 0..6249: cast feat -> fb (bf16) + f8 (fp8). blocks 6250..6265: w1/w2 transpose.
__global__ __launch_bounds__(256)
void prep(const float* __restrict__ feat, const float* __restrict__ w1,
          const float* __restrict__ w2, unsigned short* __restrict__ fb,
          unsigned char* __restrict__ f8,
          unsigned short* __restrict__ w1T, unsigned short* __restrict__ w2T) {
    if (blockIdx.x < 6250) {
        long e = ((long)blockIdx.x * 256 + threadIdx.x) * 8;   // 6250*256*8 = 12.8M exact
        float4 v0 = *(const float4*)(feat + e);
        float4 v1 = *(const float4*)(feat + e + 4);
        u16x8 ob;
        ob[0] = f2bf(v0.x); ob[1] = f2bf(v0.y); ob[2] = f2bf(v0.z); ob[3] = f2bf(v0.w);
        ob[4] = f2bf(v1.x); ob[5] = f2bf(v1.y); ob[6] = f2bf(v1.z); ob[7] = f2bf(v1.w);
        *(u16x8*)(fb + e) = ob;
        int p0 = 0, p1 = 0;
        p0 = __builtin_amdgcn_cvt_pk_fp8_f32(v0.x, v0.y, p0, false);
        p0 = __builtin_amdgcn_cvt_pk_fp8_f32(v0.z, v0.w, p0, true);
        p1 = __builtin_amdgcn_cvt_pk_fp8_f32(v1.x, v1.y, p1, false);
        p1 = __builtin_amdgcn_cvt_pk_fp8_f32(v1.z, v1.w, p1, true);
        uint2 o8; o8.x = (unsigned)p0; o8.y = (unsigned)p1;
        *(uint2*)(f8 + e) = o8;
    } else {
        int bid = blockIdx.x - 6250;
        const float* w = (bid < 8) ? w1 : w2;
        unsigned short* wT = (bid < 8) ? w1T : w2T;
        int kb = (bid & 7) * 32;
        int n = threadIdx.x & 127, dk = threadIdx.x >> 7;
#pragma unroll
        for (int i = 0; i < 16; ++i) {
            int k = kb + dk * 16 + i;
            wT[n * 256 + k] = f2bf(w[k * 128 + n]);   // read coalesced over n
        }
    }
}

// Async-DMA gather, 1-wave blocks. 8 nodes/block (8 lanes x 16 B = full 128-B row).
// No __syncthreads anywhere: the only wait is this wave's own vmcnt(0).
__global__ __launch_bounds__(64)
void k1_agg(const unsigned char* __restrict__ f8, const int* __restrict__ nbr,
            unsigned short* __restrict__ agg) {
    __shared__ unsigned char L[16][1024];   // 16 KB: [d][lane*16B] -> 10 blocks/CU
    const int lane = threadIdx.x;
    const int node = blockIdx.x * 8 + (lane >> 3);   // 12500*8 = 100000 exact
    const int sub = lane & 7;
    const int* idx = nbr + node * DEG;
    int4 i0 = *(const int4*)(idx);
    int4 i1 = *(const int4*)(idx + 4);
    int4 i2 = *(const int4*)(idx + 8);
    int4 i3 = *(const int4*)(idx + 12);
    const int id[16] = {i0.x, i0.y, i0.z, i0.w, i1.x, i1.y, i1.z, i1.w,
                        i2.x, i2.y, i2.z, i2.w, i3.x, i3.y, i3.z, i3.w};
#pragma unroll
    for (int d = 0; d < DEG; ++d) {
        const unsigned char* src = f8 + (long)id[d] * 128 + sub * 16;
        __builtin_amdgcn_global_load_lds(
            (const __attribute__((address_space(1))) unsigned int*)src,
            (__attribute__((address_space(3))) unsigned int*)(&L[d][lane * 16]),
            16, 0, 0);
    }
    asm volatile("s_waitcnt vmcnt(0)" ::: "memory");   // wave-local DMA drain

    f32x2 s2[8];
#pragma unroll
    for (int j = 0; j < 8; ++j) s2[j] = (f32x2){0.f, 0.f};
#pragma unroll
    for (int d = 0; d < DEG; ++d) {
        uint4 v = *(const uint4*)(&L[d][lane * 16]);
        s2[0] += __builtin_amdgcn_cvt_pk_f32_fp8((int)v.x, false);
        s2[1] += __builtin_amdgcn_cvt_pk_f32_fp8((int)v.x, true);
        s2[2] += __builtin_amdgcn_cvt_pk_f32_fp8((int)v.y, false);
        s2[3] += __builtin_amdgcn_cvt_pk_f32_fp8((int)v.y, true);
        s2[4] += __builtin_amdgcn_cvt_pk_f32_fp8((int)v.z, false);
        s2[5] += __builtin_amdgcn_cvt_pk_f32_fp8((int)v.z, true);
        s2[6] += __builtin_amdgcn_cvt_pk_f32_fp8((int)v.w, false);
        s2[7] += __builtin_amdgcn_cvt_pk_f32_fp8((int)v.w, true);
    }
    u16x8 o0, o1;
#pragma unroll
    for (int j = 0; j < 8; ++j) {
        o0[j] = f2bf(s2[j >> 1][j & 1] * 0.0625f);
        o1[j] = f2bf(s2[4 + (j >> 1)][j & 1] * 0.0625f);
    }
    unsigned short* dst = agg + (long)node * 128 + sub * 16;
    *(u16x8*)dst = o0;
    *(u16x8*)(dst + 8) = o1;
}

// GEMM: h1[N,128] = [fb | agg] @ w1T. 128 rows/block, 32 rows/wave.
//   - A panel (wave-private rows): 16 x bf16x8 global->VGPR, all issued up front.
//   - W (64 KB, shared): staged ONCE into LDS in MFMA-fragment order via
//     source-permuted global_load_lds (LDS dest stays lane-linear as DMA requires).
//     Chunk c = kc*8+nt is 1 KB; lane l holds (n = nt*16+(l&15), k = kc*32+(l>>4)*8..+7).
//   - ONE __syncthreads drains A-loads + W-DMA together; K-loop is pure
//     ds_read_b128 (lane-linear, conflict-free) + MFMA. No barriers, no vmem waits.
__global__ __launch_bounds__(256, 2)
void g1(const unsigned short* __restrict__ fb, const unsigned short* __restrict__ agg,
        const unsigned short* __restrict__ w1T, unsigned short* __restrict__ h1) {
    __shared__ unsigned short Wlds[64 * 512];   // 64 KB -> 2 blocks/CU
    const int t = threadIdx.x, wave = t >> 6, lane = t & 63;
    const int m16 = lane & 15, quad = lane >> 4;
    const long row0 = (long)blockIdx.x * 128 + wave * 32;

    // Issue the full A panel first: 16 outstanding 16B loads/lane (64 VGPRs).
    // Rows beyond N read the adjacent ws region (in-bounds garbage, masked on store).
    bf16x8 a[8][2];
#pragma unroll
    for (int kc = 0; kc < 8; ++kc) {
        const unsigned short* As = (kc < 4) ? (fb + kc * 32) : (agg + (kc - 4) * 32);
        a[kc][0] = *(const bf16x8*)(As + (row0 + m16) * 128 + quad * 8);
        a[kc][1] = *(const bf16x8*)(As + (row0 + 16 + m16) * 128 + quad * 8);
    }

    // Stage w1T -> LDS in fragment order. LDS dest is linear (base + lane*16);
    // the fragment permutation is applied to the GLOBAL source address.
#pragma unroll
    for (int i = 0; i < 16; ++i) {
        int o16 = i * 256 + t;            // 16B-chunk index 0..4095
        int chunk = o16 >> 6;             // = kc*8 + nt   (wave-uniform per issue)
        int kc = chunk >> 3, nt = chunk & 7;
        int n = nt * 16 + (lane & 15);
        int k0 = kc * 32 + (lane >> 4) * 8;
        const unsigned short* src = w1T + n * 256 + k0;
        __builtin_amdgcn_global_load_lds(
            (const __attribute__((address_space(1))) unsigned int*)src,
            (__attribute__((address_space(3))) unsigned int*)
                (((char*)Wlds) + (long)o16 * 16),
            16, 0, 0);
    }
    __syncthreads();   // single drain: A panel + W DMA all complete

    f32x4 acc[2][8] = {};
#pragma unroll
    for (int kc = 0; kc < 8; ++kc) {
#pragma unroll
        for (int nt = 0; nt < 8; ++nt) {
            bf16x8 bv = *(const bf16x8*)(Wlds + (kc * 8 + nt) * 512 + lane * 8);
            acc[0][nt] = __builtin_amdgcn_mfma_f32_16x16x32_bf16(a[kc][0], bv, acc[0][nt], 0, 0, 0);
            acc[1][nt] = __builtin_amdgcn_mfma_f32_16x16x32_bf16(a[kc][1], bv, acc[1][nt], 0, 0, 0);
        }
    }

    // C layout: row = quad*4 + reg, col = nt*16 + m16
#pragma unroll
    for (int mt = 0; mt < 2; ++mt)
#pragma unroll
        for (int reg = 0; reg < 4; ++reg) {
            long grow = row0 + mt * 16 + quad * 4 + reg;
            if (grow >= N_NODES) continue;
#pragma unroll
            for (int nt = 0; nt < 8; ++nt)
                h1[grow * HDIM + nt * 16 + m16] = f2bf(acc[mt][nt][reg]);
        }
}

// Layer 2 fused: 64 batch rows per 256-thread block. 128 blocks exact.
__global__ __launch_bounds__(256)
void g2_fused(const unsigned short* __restrict__ h1, const unsigned short* __restrict__ w2T,
              const int* __restrict__ nbr, const int* __restrict__ nodes,
              float* __restrict__ out) {
    __shared__ unsigned short X2[64][264];
    const int t = threadIdx.x, wave = t >> 6, lane = t & 63;
    const int m16 = lane & 15, quad = lane >> 4;
    const int b0 = blockIdx.x * 64;
    const int colb = m16 * 8;

    for (int g = 0; g < 4; ++g) {
        int Ln = wave * 16 + g * 4 + quad;
        int node = nodes[b0 + Ln];
        *(u16x8*)(&X2[Ln][colb]) = *(const u16x8*)(h1 + node * HDIM + colb);
        const int* idx = nbr + node * DEG;
        float s[8] = {0.f, 0.f, 0.f, 0.f, 0.f, 0.f, 0.f, 0.f};
#pragma unroll
        for (int d = 0; d < DEG; ++d) {
            int nb = idx[d];
            u16x8 v = *(const u16x8*)(h1 + nb * HDIM + colb);
#pragma unroll
            for (int j = 0; j < 8; ++j) s[j] += bf2f(v[j]);
        }
        u16x8 o;
#pragma unroll
        for (int j = 0; j < 8; ++j) o[j] = f2bf(s[j] * 0.0625f);
        *(u16x8*)(&X2[Ln][128 + colb]) = o;
    }
    __syncthreads();

    f32x4 acc[8] = {};
#pragma unroll
    for (int kc = 0; kc < 8; ++kc) {
        bf16x8 a = *(const bf16x8*)(&X2[wave * 16 + m16][kc * 32 + quad * 8]);
#pragma unroll
        for (int nt = 0; nt < 8; ++nt) {
            bf16x8 b = *(const bf16x8*)(w2T + (nt * 16 + m16) * 256 + kc * 32 + quad * 8);
            acc[nt] = __builtin_amdgcn_mfma_f32_16x16x32_bf16(a, b, acc[nt], 0, 0, 0);
        }
    }

#pragma unroll
    for (int nt = 0; nt < 8; ++nt)
#pragma unroll
        for (int reg = 0; reg < 4; ++reg) {
            int row = b0 + wave * 16 + quad * 4 + reg;
            out[row * 128 + nt * 16 + m16] = acc[nt][reg];
        }
}

extern "C" void kernel_launch(void* const* d_in, const int* in_sizes, int n_in,
                              void* d_out, int out_size, void* d_ws, size_t ws_size,
                              hipStream_t stream) {
    const float* feat  = (const float*)d_in[0];
    const float* w1    = (const float*)d_in[1];
    const float* w2    = (const float*)d_in[2];
    const int*   nbr   = (const int*)d_in[3];
    const int*   nodes = (const int*)d_in[4];
    float* out = (float*)d_out;

    char* ws = (char*)d_ws;
    unsigned short* fb  = (unsigned short*)ws;                       // N*128 bf16 = 25.6 MB
    unsigned char*  f8  = (unsigned char*)(ws + 25600000);           // N*128 fp8  = 12.8 MB
    unsigned short* agg = (unsigned short*)(ws + 38400000);          // N*128 bf16 = 25.6 MB
    unsigned short* h1  = (unsigned short*)(ws + 64000000);          // N*128 bf16 = 25.6 MB
    unsigned short* w1T = (unsigned short*)(ws + 89600000);          // 64 KB
    unsigned short* w2T = (unsigned short*)(ws + 89665536);          // 64 KB

    prep<<<6266, 256, 0, stream>>>(feat, w1, w2, fb, f8, w1T, w2T);
    k1_agg<<<12500, 64, 0, stream>>>(f8, nbr, agg);
    g1<<<(N_NODES + 127) / 128, 256, 0, stream>>>(fb, agg, w1T, h1);
    g2_fused<<<B_NODES / 64, 256, 0, stream>>>(h1, w2T, nbr, nodes, out);
}

// Round 3
// 169.829 us; speedup vs baseline: 1.1293x; 1.0057x over previous
//
#include <hip/hip_runtime.h>

// GraphSage on MI355X — round 12.
//   prep  : feat fp32 -> fb bf16 (GEMM self operand) + f8 fp8 e4m3 [N][128B] (gather src)
//           + w1,w2 -> w1T,w2T bf16 [n][k]
//   k1_agg: (round-9 form, known good) async-DMA gather, 1-wave blocks, wave-local
//           vmcnt(0), packed f32x2 adds. 16 KB LDS -> 10 blocks/CU.
//   g1    : h1 = [fb | agg] @ w1T. Round-9 DMA double-buffer skeleton (32 KB, 4 blk/CU)
//           + FRAGMENT-ORDER LDS (conflict-free lane-linear ds_read_b128; round-9's
//           row-major [128][32] tiles were an 8-way bank conflict) + COUNTED VMCNT
//           (raw s_barrier pairs, s_waitcnt vmcnt(4): next chunk's DMAs stay in flight
//           across the barrier instead of the __syncthreads vmcnt(0) full drain).
//           ALL global accesses remain global_load_lds DMA — hipcc serializes
//           VGPR-destination loads (round-10/11 lesson: 68 VGPR, 1 load in flight).
//   g2    : (round-9 form) out = [h1[node] | mean h1[nbr]] @ w2T, 64 rows/block.

#define N_NODES 100000
#define DEG     16
#define FDIM    128
#define HDIM    128
#define B_NODES 8192

typedef __attribute__((ext_vector_type(8))) short bf16x8;
typedef __attribute__((ext_vector_type(8))) unsigned short u16x8;
typedef __attribute__((ext_vector_type(4))) float f32x4;
typedef __attribute__((ext_vector_type(2))) float f32x2;

static __device__ __forceinline__ unsigned short f2bf(float f) {
    union { float f; unsigned u; } v; v.f = f;
    unsigned r = v.u + 0x7fff + ((v.u >> 16) & 1);   // RNE
    return (unsigned short)(r >> 16);
}
static __device__ __forceinline__ float bf2f(unsigned short b) {
    union { unsigned u; float f; } v; v.u = ((unsigned)b) << 16;
    return v.f;
}

// blocks 0..6249: cast feat -> fb (bf16) + f8 (fp8). blocks 6250..6265: w1/w2 transpose.
__global__ __launch_bounds__(256)
void prep(const float* __restrict__ feat, const float* __restrict__ w1,
          const float* __restrict__ w2, unsigned short* __restrict__ fb,
          unsigned char* __restrict__ f8,
          unsigned short* __restrict__ w1T, unsigned short* __restrict__ w2T) {
    if (blockIdx.x < 6250) {
        long e = ((long)blockIdx.x * 256 + threadIdx.x) * 8;   // 6250*256*8 = 12.8M exact
        float4 v0 = *(const float4*)(feat + e);
        float4 v1 = *(const float4*)(feat + e + 4);
        u16x8 ob;
        ob[0] = f2bf(v0.x); ob[1] = f2bf(v0.y); ob[2] = f2bf(v0.z); ob[3] = f2bf(v0.w);
        ob[4] = f2bf(v1.x); ob[5] = f2bf(v1.y); ob[6] = f2bf(v1.z); ob[7] = f2bf(v1.w);
        *(u16x8*)(fb + e) = ob;
        int p0 = 0, p1 = 0;
        p0 = __builtin_amdgcn_cvt_pk_fp8_f32(v0.x, v0.y, p0, false);
        p0 = __builtin_amdgcn_cvt_pk_fp8_f32(v0.z, v0.w, p0, true);
        p1 = __builtin_amdgcn_cvt_pk_fp8_f32(v1.x, v1.y, p1, false);
        p1 = __builtin_amdgcn_cvt_pk_fp8_f32(v1.z, v1.w, p1, true);
        uint2 o8; o8.x = (unsigned)p0; o8.y = (unsigned)p1;
        *(uint2*)(f8 + e) = o8;
    } else {
        int bid = blockIdx.x - 6250;
        const float* w = (bid < 8) ? w1 : w2;
        unsigned short* wT = (bid < 8) ? w1T : w2T;
        int kb = (bid & 7) * 32;
        int n = threadIdx.x & 127, dk = threadIdx.x >> 7;
#pragma unroll
        for (int i = 0; i < 16; ++i) {
            int k = kb + dk * 16 + i;
            wT[n * 256 + k] = f2bf(w[k * 128 + n]);   // read coalesced over n
        }
    }
}

// Async-DMA gather, 1-wave blocks. 8 nodes/block (8 lanes x 16 B = full 128-B row).
// No __syncthreads anywhere: the only wait is this wave's own vmcnt(0).
__global__ __launch_bounds__(64)
void k1_agg(const unsigned char* __restrict__ f8, const int* __restrict__ nbr,
            unsigned short* __restrict__ agg) {
    __shared__ unsigned char L[16][1024];   // 16 KB: [d][lane*16B] -> 10 blocks/CU
    const int lane = threadIdx.x;
    const int node = blockIdx.x * 8 + (lane >> 3);   // 12500*8 = 100000 exact
    const int sub = lane & 7;
    const int* idx = nbr + node * DEG;
    int4 i0 = *(const int4*)(idx);
    int4 i1 = *(const int4*)(idx + 4);
    int4 i2 = *(const int4*)(idx + 8);
    int4 i3 = *(const int4*)(idx + 12);
    const int id[16] = {i0.x, i0.y, i0.z, i0.w, i1.x, i1.y, i1.z, i1.w,
                        i2.x, i2.y, i2.z, i2.w, i3.x, i3.y, i3.z, i3.w};
#pragma unroll
    for (int d = 0; d < DEG; ++d) {
        const unsigned char* src = f8 + (long)id[d] * 128 + sub * 16;
        __builtin_amdgcn_global_load_lds(
            (const __attribute__((address_space(1))) unsigned int*)src,
            (__attribute__((address_space(3))) unsigned int*)(&L[d][lane * 16]),
            16, 0, 0);
    }
    asm volatile("s_waitcnt vmcnt(0)" ::: "memory");   // wave-local DMA drain

    f32x2 s2[8];
#pragma unroll
    for (int j = 0; j < 8; ++j) s2[j] = (f32x2){0.f, 0.f};
#pragma unroll
    for (int d = 0; d < DEG; ++d) {
        uint4 v = *(const uint4*)(&L[d][lane * 16]);
        s2[0] += __builtin_amdgcn_cvt_pk_f32_fp8((int)v.x, false);
        s2[1] += __builtin_amdgcn_cvt_pk_f32_fp8((int)v.x, true);
        s2[2] += __builtin_amdgcn_cvt_pk_f32_fp8((int)v.y, false);
        s2[3] += __builtin_amdgcn_cvt_pk_f32_fp8((int)v.y, true);
        s2[4] += __builtin_amdgcn_cvt_pk_f32_fp8((int)v.z, false);
        s2[5] += __builtin_amdgcn_cvt_pk_f32_fp8((int)v.z, true);
        s2[6] += __builtin_amdgcn_cvt_pk_f32_fp8((int)v.w, false);
        s2[7] += __builtin_amdgcn_cvt_pk_f32_fp8((int)v.w, true);
    }
    u16x8 o0, o1;
#pragma unroll
    for (int j = 0; j < 8; ++j) {
        o0[j] = f2bf(s2[j >> 1][j & 1] * 0.0625f);
        o1[j] = f2bf(s2[4 + (j >> 1)][j & 1] * 0.0625f);
    }
    unsigned short* dst = agg + (long)node * 128 + sub * 16;
    *(u16x8*)dst = o0;
    *(u16x8*)(dst + 8) = o1;
}

// Stage K-chunk KC (A: 128 rows x 32 k, W: 128 n x 32 k; 8 KB each) into buf BUF,
// in MFMA-FRAGMENT order: 1 KB sub-chunk `sub` holds (row/n = sub*16..+15 pattern,
// k = quad*8) at lane-linear dest base + lane*16B. 4 DMA / thread.
//   A sub-chunk sub = w*2+mt  -> row = (sub>>1)*32 + (sub&1)*16 + m16
//   W sub-chunk sub = nt      -> n   = sub*16 + m16
// Dest ushort offset (j*256+t)*8 == sub*512 + lane*8 (since sub = j*4+wave). Verified:
// 512*(4j+wave) + lane*8 == (j*256 + wave*64 + lane)*8.
#define STAGE1(KC, BUF)                                                                   \
    do {                                                                                  \
        const int kc_ = (KC);                                                             \
        const unsigned short* Asel_ =                                                     \
            (kc_ < 4) ? (fb + kc_ * 32) : (agg + (kc_ - 4) * 32);                         \
        _Pragma("unroll")                                                                 \
        for (int j_ = 0; j_ < 2; ++j_) {                                                  \
            int sub_ = j_ * 4 + wave;                                                     \
            int rowA_ = (sub_ >> 1) * 32 + (sub_ & 1) * 16 + m16;                         \
            const unsigned short* ga_ = Asel_ + (row0 + rowA_) * 128 + quad * 8;          \
            __builtin_amdgcn_global_load_lds(                                             \
                (const __attribute__((address_space(1))) unsigned int*)ga_,               \
                (__attribute__((address_space(3))) unsigned int*)                         \
                    (&As_[BUF][(j_ * 256 + t) * 8]), 16, 0, 0);                           \
            int n_ = sub_ * 16 + m16;                                                     \
            const unsigned short* gw_ = w1T + n_ * 256 + kc_ * 32 + quad * 8;             \
            __builtin_amdgcn_global_load_lds(                                             \
                (const __attribute__((address_space(1))) unsigned int*)gw_,               \
                (__attribute__((address_space(3))) unsigned int*)                         \
                    (&Ws_[BUF][(j_ * 256 + t) * 8]), 16, 0, 0);                           \
        }                                                                                 \
    } while (0)

// GEMM: h1[N,128] = [fb | agg] @ w1T. 128 rows/block, BK=32, double-buffered DMA.
// Counted-vmcnt pipeline, 2 raw barriers/chunk:
//   B1 (buf[(kc+1)&1] free) -> STAGE(kc+1) -> vmcnt(4) (chunk kc landed, kc+1 flying)
//   -> B2 (all waves' stage visible) -> 16x2 MFMA on conflict-free lane-linear frags.
__global__ __launch_bounds__(256, 4)
void g1(const unsigned short* __restrict__ fb, const unsigned short* __restrict__ agg,
        const unsigned short* __restrict__ w1T, unsigned short* __restrict__ h1) {
    __shared__ unsigned short As_[2][4096];   // 8 KB per buf
    __shared__ unsigned short Ws_[2][4096];
    const int t = threadIdx.x, wave = t >> 6, lane = t & 63;
    const int m16 = lane & 15, quad = lane >> 4;
    const long row0 = (long)blockIdx.x * 128;

    f32x4 acc[2][8] = {};
    STAGE1(0, 0);
#pragma unroll
    for (int kc = 0; kc < 8; ++kc) {
        __builtin_amdgcn_s_barrier();            // B1: all waves done reading chunk kc-1
        __builtin_amdgcn_sched_barrier(0);
        if (kc < 7) {
            STAGE1(kc + 1, (kc + 1) & 1);        // into the buf chunk kc-1 vacated
            asm volatile("s_waitcnt vmcnt(4)" ::: "memory");   // chunk kc landed (mine)
        } else {
            asm volatile("s_waitcnt vmcnt(0)" ::: "memory");
        }
        __builtin_amdgcn_s_barrier();            // B2: everyone's chunk-kc DMAs visible
        __builtin_amdgcn_sched_barrier(0);

        const unsigned short* Ab = As_[kc & 1];
        const unsigned short* Wb = Ws_[kc & 1];
        bf16x8 a0 = *(const bf16x8*)(Ab + (wave * 2 + 0) * 512 + lane * 8);
        bf16x8 a1 = *(const bf16x8*)(Ab + (wave * 2 + 1) * 512 + lane * 8);
#pragma unroll
        for (int nt = 0; nt < 8; ++nt) {
            bf16x8 bv = *(const bf16x8*)(Wb + nt * 512 + lane * 8);
            acc[0][nt] = __builtin_amdgcn_mfma_f32_16x16x32_bf16(a0, bv, acc[0][nt], 0, 0, 0);
            acc[1][nt] = __builtin_amdgcn_mfma_f32_16x16x32_bf16(a1, bv, acc[1][nt], 0, 0, 0);
        }
    }

    // C layout: row = quad*4 + reg, col = nt*16 + m16
#pragma unroll
    for (int mt = 0; mt < 2; ++mt)
#pragma unroll
        for (int reg = 0; reg < 4; ++reg) {
            long grow = row0 + wave * 32 + mt * 16 + quad * 4 + reg;
            if (grow >= N_NODES) continue;
#pragma unroll
            for (int nt = 0; nt < 8; ++nt)
                h1[grow * HDIM + nt * 16 + m16] = f2bf(acc[mt][nt][reg]);
        }
}

// Layer 2 fused: 64 batch rows per 256-thread block. 128 blocks exact.
__global__ __launch_bounds__(256)
void g2_fused(const unsigned short* __restrict__ h1, const unsigned short* __restrict__ w2T,
              const int* __restrict__ nbr, const int* __restrict__ nodes,
              float* __restrict__ out) {
    __shared__ unsigned short X2[64][264];
    const int t = threadIdx.x, wave = t >> 6, lane = t & 63;
    const int m16 = lane & 15, quad = lane >> 4;
    const int b0 = blockIdx.x * 64;
    const int colb = m16 * 8;

    for (int g = 0; g < 4; ++g) {
        int Ln = wave * 16 + g * 4 + quad;
        int node = nodes[b0 + Ln];
        *(u16x8*)(&X2[Ln][colb]) = *(const u16x8*)(h1 + node * HDIM + colb);
        const int* idx = nbr + node * DEG;
        float s[8] = {0.f, 0.f, 0.f, 0.f, 0.f, 0.f, 0.f, 0.f};
#pragma unroll
        for (int d = 0; d < DEG; ++d) {
            int nb = idx[d];
            u16x8 v = *(const u16x8*)(h1 + nb * HDIM + colb);
#pragma unroll
            for (int j = 0; j < 8; ++j) s[j] += bf2f(v[j]);
        }
        u16x8 o;
#pragma unroll
        for (int j = 0; j < 8; ++j) o[j] = f2bf(s[j] * 0.0625f);
        *(u16x8*)(&X2[Ln][128 + colb]) = o;
    }
    __syncthreads();

    f32x4 acc[8] = {};
#pragma unroll
    for (int kc = 0; kc < 8; ++kc) {
        bf16x8 a = *(const bf16x8*)(&X2[wave * 16 + m16][kc * 32 + quad * 8]);
#pragma unroll
        for (int nt = 0; nt < 8; ++nt) {
            bf16x8 b = *(const bf16x8*)(w2T + (nt * 16 + m16) * 256 + kc * 32 + quad * 8);
            acc[nt] = __builtin_amdgcn_mfma_f32_16x16x32_bf16(a, b, acc[nt], 0, 0, 0);
        }
    }

#pragma unroll
    for (int nt = 0; nt < 8; ++nt)
#pragma unroll
        for (int reg = 0; reg < 4; ++reg) {
            int row = b0 + wave * 16 + quad * 4 + reg;
            out[row * 128 + nt * 16 + m16] = acc[nt][reg];
        }
}

extern "C" void kernel_launch(void* const* d_in, const int* in_sizes, int n_in,
                              void* d_out, int out_size, void* d_ws, size_t ws_size,
                              hipStream_t stream) {
    const float* feat  = (const float*)d_in[0];
    const float* w1    = (const float*)d_in[1];
    const float* w2    = (const float*)d_in[2];
    const int*   nbr   = (const int*)d_in[3];
    const int*   nodes = (const int*)d_in[4];
    float* out = (float*)d_out;

    char* ws = (char*)d_ws;
    unsigned short* fb  = (unsigned short*)ws;                       // N*128 bf16 = 25.6 MB
    unsigned char*  f8  = (unsigned char*)(ws + 25600000);           // N*128 fp8  = 12.8 MB
    unsigned short* agg = (unsigned short*)(ws + 38400000);          // N*128 bf16 = 25.6 MB
    unsigned short* h1  = (unsigned short*)(ws + 64000000);          // N*128 bf16 = 25.6 MB
    unsigned short* w1T = (unsigned short*)(ws + 89600000);          // 64 KB
    unsigned short* w2T = (unsigned short*)(ws + 89665536);          // 64 KB

    prep<<<6266, 256, 0, stream>>>(feat, w1, w2, fb, f8, w1T, w2T);
    k1_agg<<<12500, 64, 0, stream>>>(f8, nbr, agg);
    g1<<<(N_NODES + 127) / 128, 256, 0, stream>>>(fb, agg, w1T, h1);
    g2_fused<<<B_NODES / 64, 256, 0, stream>>>(h1, w2T, nbr, nodes, out);
}

// Round 5
// 165.787 us; speedup vs baseline: 1.1568x; 1.0244x over previous
//
#include <hip/hip_runtime.h>

// GraphSage on MI355X — round 14 (round 13 with the asm-tie compile fix).
//   prep  : feat fp32 -> fb bf16 (GEMM self operand) + f8 fp8 e4m3 [N][128B] (gather src)
//           + w1,w2 -> w1T,w2T bf16 [n][k]
//   k1_agg: quarter-buffer pipelined DMA gather (2 x 4KB bufs, counted vmcnt(4)):
//           convert quarter q while q+1 flies; 8KB LDS -> 20 blocks/CU (was 10).
//           Sum order d0..d15 unchanged -> bitwise identical results.
//   g1    : EXACT round-9 form (best measured; later variants were +5us each).
//   g2    : round-9 structure + inline-asm parallel neighbor loads (16 in flight).
//           Waitcnt is a plain asm + sched_barrier(0) (rule #18): clang rejects
//           tied ext-vector "+v" operands ("tied indirect register inputs").

#define N_NODES 100000
#define DEG     16
#define FDIM    128
#define HDIM    128
#define B_NODES 8192

typedef __attribute__((ext_vector_type(8))) short bf16x8;
typedef __attribute__((ext_vector_type(8))) unsigned short u16x8;
typedef __attribute__((ext_vector_type(4))) float f32x4;
typedef __attribute__((ext_vector_type(2))) float f32x2;

static __device__ __forceinline__ unsigned short f2bf(float f) {
    union { float f; unsigned u; } v; v.f = f;
    unsigned r = v.u + 0x7fff + ((v.u >> 16) & 1);   // RNE
    return (unsigned short)(r >> 16);
}
static __device__ __forceinline__ float bf2f(unsigned short b) {
    union { unsigned u; float f; } v; v.u = ((unsigned)b) << 16;
    return v.f;
}

// blocks 0..6249: cast feat -> fb (bf16) + f8 (fp8). blocks 6250..6265: w1/w2 transpose.
__global__ __launch_bounds__(256)
void prep(const float* __restrict__ feat, const float* __restrict__ w1,
          const float* __restrict__ w2, unsigned short* __restrict__ fb,
          unsigned char* __restrict__ f8,
          unsigned short* __restrict__ w1T, unsigned short* __restrict__ w2T) {
    if (blockIdx.x < 6250) {
        long e = ((long)blockIdx.x * 256 + threadIdx.x) * 8;   // 6250*256*8 = 12.8M exact
        float4 v0 = *(const float4*)(feat + e);
        float4 v1 = *(const float4*)(feat + e + 4);
        u16x8 ob;
        ob[0] = f2bf(v0.x); ob[1] = f2bf(v0.y); ob[2] = f2bf(v0.z); ob[3] = f2bf(v0.w);
        ob[4] = f2bf(v1.x); ob[5] = f2bf(v1.y); ob[6] = f2bf(v1.z); ob[7] = f2bf(v1.w);
        *(u16x8*)(fb + e) = ob;
        int p0 = 0, p1 = 0;
        p0 = __builtin_amdgcn_cvt_pk_fp8_f32(v0.x, v0.y, p0, false);
        p0 = __builtin_amdgcn_cvt_pk_fp8_f32(v0.z, v0.w, p0, true);
        p1 = __builtin_amdgcn_cvt_pk_fp8_f32(v1.x, v1.y, p1, false);
        p1 = __builtin_amdgcn_cvt_pk_fp8_f32(v1.z, v1.w, p1, true);
        uint2 o8; o8.x = (unsigned)p0; o8.y = (unsigned)p1;
        *(uint2*)(f8 + e) = o8;
    } else {
        int bid = blockIdx.x - 6250;
        const float* w = (bid < 8) ? w1 : w2;
        unsigned short* wT = (bid < 8) ? w1T : w2T;
        int kb = (bid & 7) * 32;
        int n = threadIdx.x & 127, dk = threadIdx.x >> 7;
#pragma unroll
        for (int i = 0; i < 16; ++i) {
            int k = kb + dk * 16 + i;
            wT[n * 256 + k] = f2bf(w[k * 128 + n]);   // read coalesced over n
        }
    }
}

// Quarter-buffer pipelined gather. 8 nodes/block, 1 wave, no barriers.
// Two 4KB buffers; convert quarter q overlaps quarter q+1's DMA flight.
__global__ __launch_bounds__(64)
void k1_agg(const unsigned char* __restrict__ f8, const int* __restrict__ nbr,
            unsigned short* __restrict__ agg) {
    __shared__ unsigned char L[8][1024];   // 8 KB -> 20 blocks/CU (was 16 KB / 10)
    const int lane = threadIdx.x;
    const int node = blockIdx.x * 8 + (lane >> 3);   // 12500*8 = 100000 exact
    const int sub = lane & 7;
    const int* idx = nbr + node * DEG;
    int4 i0 = *(const int4*)(idx);
    int4 i1 = *(const int4*)(idx + 4);
    int4 i2 = *(const int4*)(idx + 8);
    int4 i3 = *(const int4*)(idx + 12);
    const int id[16] = {i0.x, i0.y, i0.z, i0.w, i1.x, i1.y, i1.z, i1.w,
                        i2.x, i2.y, i2.z, i2.w, i3.x, i3.y, i3.z, i3.w};

#define K1_ISSUE(Q, B)                                                          \
    _Pragma("unroll")                                                           \
    for (int j_ = 0; j_ < 4; ++j_) {                                            \
        const unsigned char* src_ = f8 + (long)id[(Q) * 4 + j_] * 128 + sub * 16; \
        __builtin_amdgcn_global_load_lds(                                       \
            (const __attribute__((address_space(1))) unsigned int*)src_,        \
            (__attribute__((address_space(3))) unsigned int*)                   \
                (&L[(B) * 4 + j_][lane * 16]), 16, 0, 0);                       \
    }

    f32x2 s2[8];
#pragma unroll
    for (int j = 0; j < 8; ++j) s2[j] = (f32x2){0.f, 0.f};

#define K1_CONV(B)                                                              \
    _Pragma("unroll")                                                           \
    for (int j_ = 0; j_ < 4; ++j_) {                                            \
        uint4 v = *(const uint4*)(&L[(B) * 4 + j_][lane * 16]);                 \
        s2[0] += __builtin_amdgcn_cvt_pk_f32_fp8((int)v.x, false);              \
        s2[1] += __builtin_amdgcn_cvt_pk_f32_fp8((int)v.x, true);               \
        s2[2] += __builtin_amdgcn_cvt_pk_f32_fp8((int)v.y, false);              \
        s2[3] += __builtin_amdgcn_cvt_pk_f32_fp8((int)v.y, true);               \
        s2[4] += __builtin_amdgcn_cvt_pk_f32_fp8((int)v.z, false);              \
        s2[5] += __builtin_amdgcn_cvt_pk_f32_fp8((int)v.z, true);               \
        s2[6] += __builtin_amdgcn_cvt_pk_f32_fp8((int)v.w, false);              \
        s2[7] += __builtin_amdgcn_cvt_pk_f32_fp8((int)v.w, true);               \
    }

    K1_ISSUE(0, 0);
    K1_ISSUE(1, 1);
    asm volatile("s_waitcnt vmcnt(4)" ::: "memory");   // q0 landed, q1 flying
    __builtin_amdgcn_sched_barrier(0);
    K1_CONV(0);                                        // d0..3
    __builtin_amdgcn_sched_barrier(0);
    K1_ISSUE(2, 0);                                    // reuse buf0
    asm volatile("s_waitcnt vmcnt(4)" ::: "memory");   // q1 landed, q2 flying
    __builtin_amdgcn_sched_barrier(0);
    K1_CONV(1);                                        // d4..7
    __builtin_amdgcn_sched_barrier(0);
    K1_ISSUE(3, 1);                                    // reuse buf1
    asm volatile("s_waitcnt vmcnt(4)" ::: "memory");   // q2 landed, q3 flying
    __builtin_amdgcn_sched_barrier(0);
    K1_CONV(0);                                        // d8..11
    asm volatile("s_waitcnt vmcnt(0)" ::: "memory");   // q3 landed
    __builtin_amdgcn_sched_barrier(0);
    K1_CONV(1);                                        // d12..15

    u16x8 o0, o1;
#pragma unroll
    for (int j = 0; j < 8; ++j) {
        o0[j] = f2bf(s2[j >> 1][j & 1] * 0.0625f);
        o1[j] = f2bf(s2[4 + (j >> 1)][j & 1] * 0.0625f);
    }
    unsigned short* dst = agg + (long)node * 128 + sub * 16;
    *(u16x8*)dst = o0;
    *(u16x8*)(dst + 8) = o1;
}

// Stage one K-chunk (A rows + W rows, 8 KB each) into LDS buf via global_load_lds.
#define STAGE(KC, BUF)                                                                        \
    do {                                                                                      \
        const unsigned short* s0_ = ((KC) < 4) ? (fb + (KC) * 32) : (agg + ((KC) - 4) * 32);  \
        _Pragma("unroll")                                                                     \
        for (int j_ = 0; j_ < 2; ++j_) {                                                      \
            long grow_ = row0 + (t >> 2) + j_ * 64;                                           \
            const unsigned short* ga_ = s0_ + grow_ * 128 + (t & 3) * 8;                      \
            __builtin_amdgcn_global_load_lds(                                                 \
                (const __attribute__((address_space(1))) unsigned int*)ga_,                   \
                (__attribute__((address_space(3))) unsigned int*)                             \
                    (&AsS[(BUF) * 4096 + wave * 512 + j_ * 2048 + lane * 8]), 16, 0, 0);      \
            const unsigned short* gw_ = w1T + ((t >> 2) + j_ * 64) * 256 + (KC) * 32 + (t & 3) * 8; \
            __builtin_amdgcn_global_load_lds(                                                 \
                (const __attribute__((address_space(1))) unsigned int*)gw_,                   \
                (__attribute__((address_space(3))) unsigned int*)                             \
                    (&WsS[(BUF) * 4096 + wave * 512 + j_ * 2048 + lane * 8]), 16, 0, 0);      \
        }                                                                                     \
    } while (0)

// GEMM: h1[N,128] = [fb | agg] @ w1T. 128 rows/block, BK=32, double-buffered async LDS.
// 4 blocks/CU: staging-latency-bound, so TLP is the lever (MFMA ~6% of cycles).
// EXACT round-9 form — best measured of four variants tried.
__global__ __launch_bounds__(256, 4)
void g1(const unsigned short* __restrict__ fb, const unsigned short* __restrict__ agg,
        const unsigned short* __restrict__ w1T, unsigned short* __restrict__ h1) {
    __shared__ unsigned short AsS[2 * 4096];   // 2 x 128 rows x 32 k (8 KB each)
    __shared__ unsigned short WsS[2 * 4096];
    const int t = threadIdx.x, wave = t >> 6, lane = t & 63;
    const int m16 = lane & 15, quad = lane >> 4;
    const long row0 = (long)blockIdx.x * 128;

    f32x4 acc[2][8] = {};
    STAGE(0, 0);
#pragma unroll
    for (int kc = 0; kc < 8; ++kc) {
        __syncthreads();                       // drains vmcnt -> staging of kc complete
        if (kc < 7) {
            switch (kc + 1) {
                case 1: STAGE(1, 1); break;
                case 2: STAGE(2, 0); break;
                case 3: STAGE(3, 1); break;
                case 4: STAGE(4, 0); break;
                case 5: STAGE(5, 1); break;
                case 6: STAGE(6, 0); break;
                case 7: STAGE(7, 1); break;
            }
        }
        const unsigned short* Ab = &AsS[(kc & 1) * 4096];
        const unsigned short* Wb = &WsS[(kc & 1) * 4096];
        bf16x8 a0 = *(const bf16x8*)(Ab + (wave * 32 + m16) * 32 + quad * 8);
        bf16x8 a1 = *(const bf16x8*)(Ab + (wave * 32 + 16 + m16) * 32 + quad * 8);
#pragma unroll
        for (int nt = 0; nt < 8; ++nt) {
            bf16x8 bv = *(const bf16x8*)(Wb + (nt * 16 + m16) * 32 + quad * 8);
            acc[0][nt] = __builtin_amdgcn_mfma_f32_16x16x32_bf16(a0, bv, acc[0][nt], 0, 0, 0);
            acc[1][nt] = __builtin_amdgcn_mfma_f32_16x16x32_bf16(a1, bv, acc[1][nt], 0, 0, 0);
        }
    }

    // C layout: row = quad*4 + reg, col = nt*16 + m16
#pragma unroll
    for (int mt = 0; mt < 2; ++mt)
#pragma unroll
        for (int reg = 0; reg < 4; ++reg) {
            long grow = row0 + wave * 32 + mt * 16 + quad * 4 + reg;
            if (grow >= N_NODES) continue;
#pragma unroll
            for (int nt = 0; nt < 8; ++nt)
                h1[grow * HDIM + nt * 16 + m16] = f2bf(acc[mt][nt][reg]);
        }
}

// Layer 2 fused: 64 batch rows per 256-thread block. 128 blocks exact.
// Neighbor gather uses inline-asm loads so all 16 rows are in flight at once.
__global__ __launch_bounds__(256)
void g2_fused(const unsigned short* __restrict__ h1, const unsigned short* __restrict__ w2T,
              const int* __restrict__ nbr, const int* __restrict__ nodes,
              float* __restrict__ out) {
    __shared__ unsigned short X2[64][264];
    const int t = threadIdx.x, wave = t >> 6, lane = t & 63;
    const int m16 = lane & 15, quad = lane >> 4;
    const int b0 = blockIdx.x * 64;
    const int colb = m16 * 8;

    for (int g = 0; g < 4; ++g) {
        int Ln = wave * 16 + g * 4 + quad;
        int node = nodes[b0 + Ln];
        *(u16x8*)(&X2[Ln][colb]) = *(const u16x8*)(h1 + (long)node * HDIM + colb);
        const int* idx = nbr + node * DEG;
        int4 i0 = *(const int4*)(idx);
        int4 i1 = *(const int4*)(idx + 4);
        int4 i2 = *(const int4*)(idx + 8);
        int4 i3 = *(const int4*)(idx + 12);
        const int id[16] = {i0.x, i0.y, i0.z, i0.w, i1.x, i1.y, i1.z, i1.w,
                            i2.x, i2.y, i2.z, i2.w, i3.x, i3.y, i3.z, i3.w};

        uint4 v0, v1, v2, v3, v4, v5, v6, v7, v8, v9, v10, v11, v12, v13, v14, v15;
#define G2_LOAD(K)                                                               \
        {                                                                        \
            unsigned long long a_ =                                              \
                (unsigned long long)(h1 + (long)id[K] * HDIM + colb);            \
            asm volatile("global_load_dwordx4 %0, %1, off"                       \
                         : "=v"(v##K) : "v"(a_) : "memory");                     \
        }
        G2_LOAD(0)  G2_LOAD(1)  G2_LOAD(2)  G2_LOAD(3)
        G2_LOAD(4)  G2_LOAD(5)  G2_LOAD(6)  G2_LOAD(7)
        G2_LOAD(8)  G2_LOAD(9)  G2_LOAD(10) G2_LOAD(11)
        G2_LOAD(12) G2_LOAD(13) G2_LOAD(14) G2_LOAD(15)
#undef G2_LOAD

        float s[8] = {0.f, 0.f, 0.f, 0.f, 0.f, 0.f, 0.f, 0.f};
        // first 8 rows ready; last 8 still flying (rule #18: waitcnt + sched_barrier)
        asm volatile("s_waitcnt vmcnt(8)" ::: "memory");
        __builtin_amdgcn_sched_barrier(0);
#define G2_SUM(K)                                                                \
        {                                                                        \
            u16x8 w_ = __builtin_bit_cast(u16x8, v##K);                          \
            _Pragma("unroll")                                                    \
            for (int j = 0; j < 8; ++j) s[j] += bf2f(w_[j]);                     \
        }
        G2_SUM(0) G2_SUM(1) G2_SUM(2) G2_SUM(3)
        G2_SUM(4) G2_SUM(5) G2_SUM(6) G2_SUM(7)
        asm volatile("s_waitcnt vmcnt(0)" ::: "memory");
        __builtin_amdgcn_sched_barrier(0);
        G2_SUM(8)  G2_SUM(9)  G2_SUM(10) G2_SUM(11)
        G2_SUM(12) G2_SUM(13) G2_SUM(14) G2_SUM(15)
#undef G2_SUM

        u16x8 o;
#pragma unroll
        for (int j = 0; j < 8; ++j) o[j] = f2bf(s[j] * 0.0625f);
        *(u16x8*)(&X2[Ln][128 + colb]) = o;
    }
    __syncthreads();

    f32x4 acc[8] = {};
#pragma unroll
    for (int kc = 0; kc < 8; ++kc) {
        bf16x8 a = *(const bf16x8*)(&X2[wave * 16 + m16][kc * 32 + quad * 8]);
#pragma unroll
        for (int nt = 0; nt < 8; ++nt) {
            bf16x8 b = *(const bf16x8*)(w2T + (nt * 16 + m16) * 256 + kc * 32 + quad * 8);
            acc[nt] = __builtin_amdgcn_mfma_f32_16x16x32_bf16(a, b, acc[nt], 0, 0, 0);
        }
    }

#pragma unroll
    for (int nt = 0; nt < 8; ++nt)
#pragma unroll
        for (int reg = 0; reg < 4; ++reg) {
            int row = b0 + wave * 16 + quad * 4 + reg;
            out[(long)row * 128 + nt * 16 + m16] = acc[nt][reg];
        }
}

extern "C" void kernel_launch(void* const* d_in, const int* in_sizes, int n_in,
                              void* d_out, int out_size, void* d_ws, size_t ws_size,
                              hipStream_t stream) {
    const float* feat  = (const float*)d_in[0];
    const float* w1    = (const float*)d_in[1];
    const float* w2    = (const float*)d_in[2];
    const int*   nbr   = (const int*)d_in[3];
    const int*   nodes = (const int*)d_in[4];
    float* out = (float*)d_out;

    char* ws = (char*)d_ws;
    unsigned short* fb  = (unsigned short*)ws;                       // N*128 bf16 = 25.6 MB
    unsigned char*  f8  = (unsigned char*)(ws + 25600000);           // N*128 fp8  = 12.8 MB
    unsigned short* agg = (unsigned short*)(ws + 38400000);          // N*128 bf16 = 25.6 MB
    unsigned short* h1  = (unsigned short*)(ws + 64000000);          // N*128 bf16 = 25.6 MB
    unsigned short* w1T = (unsigned short*)(ws + 89600000);          // 64 KB
    unsigned short* w2T = (unsigned short*)(ws + 89665536);          // 64 KB

    prep<<<6266, 256, 0, stream>>>(feat, w1, w2, fb, f8, w1T, w2T);
    k1_agg<<<12500, 64, 0, stream>>>(f8, nbr, agg);
    g1<<<(N_NODES + 127) / 128, 256, 0, stream>>>(fb, agg, w1T, h1);
    g2_fused<<<B_NODES / 64, 256, 0, stream>>>(h1, w2T, nbr, nodes, out);
}